// Round 4
// baseline (593.184 us; speedup 1.0000x reference)
//
#include <hip/hip_runtime.h>

// Masked inclusive cumsum along rows: out[r, :] = cumsum(where(mask, x, 0), axis=1)
// ROWS=2048, N=32768.
//
// R6: barrier-free wave-granularity chained scan.
// History: R0 (row/block, 3 barriers) 176us @3.07 TB/s; R4/R5 (256-thr
// lookback, 6-8 blk/CU) 197-213us @2.5-2.7 TB/s. Occupancy 41->82% did NOT
// move bandwidth -> limiter is load-issue density, not residency: barriers
// phase-lock all co-resident blocks (same generation, identical work) into
// load-burst / scan-hole / store-burst convoys; ~85% of time all waves sit
// in s_waitcnt while HBM runs at 43%.
//
// Fix: no barriers at all. Each 64-lane WAVE owns one 2048-element segment
// fully in registers: 8xfloat4 + 8xint4 loads (all in flight; 128-VGPR
// budget via launch_bounds(256,4)), per-float4 prefix, 8 shuffle wave-scans
// with running carry, wave-level lookback on a per-(row,seg) flag chain
// (16 segs/row), __shfl broadcast, store. Zero LDS, zero __syncthreads ->
// waves drift freely and some wave is always issuing memory.
//
// Chain handoff: one 64-bit word per (seg,row): [63:32]=ready, [31:0]=float
// bits of inclusive row prefix. Payload+flag in one atom -> relaxed
// agent-scope atomics. Flags zeroed by hipMemsetAsync each launch.
// Grid is segment-major (all sblk=0 blocks first): a wave waits only on
// earlier-dispatched segments -> no deadlock (CP dispatches in ID order).

#define ROWS    2048
#define NCOL    32768
#define THREADS 256
#define WPB     (THREADS / 64)        // 4 waves per block
#define KCH     8                     // float4-chunks per lane
#define SEGE    (64 * KCH * 4)        // 2048 elements per wave-segment
#define NSEG    (NCOL / SEGE)         // 16 segments per row
#define BPR     (NSEG / WPB)          // 4 blocks per row

static_assert(ROWS == 2048, "row decode uses & 2047");
static_assert(NSEG * SEGE == NCOL, "exact tiling");
static_assert(BPR * WPB == NSEG, "exact wave tiling");

__global__ __launch_bounds__(THREADS, 4) void masked_cumsum_wavechain(
    const float* __restrict__ x,
    const int*   __restrict__ mask,
    float*       __restrict__ out,
    unsigned long long* __restrict__ flags)
{
    const int bid  = blockIdx.x;
    const int sblk = bid >> 11;               // segment-major: sblk = bid / ROWS
    const int row  = bid & (ROWS - 1);
    const int lane = threadIdx.x & 63;
    const int wave = threadIdx.x >> 6;
    const int seg  = sblk * WPB + wave;       // 0..NSEG-1

    const size_t base = (size_t)row * NCOL + (size_t)seg * SEGE;
    const float4* __restrict__ xs = (const float4*)(x + base);
    const int4*   __restrict__ ms = (const int4*)(mask + base);
    float4*       __restrict__ os = (float4*)(out + base);

    // ---- Load the whole segment into registers: 16 independent 16B loads.
    float4 xv[KCH];
    int4   mv[KCH];
    #pragma unroll
    for (int k = 0; k < KCH; ++k) xv[k] = xs[k * 64 + lane];
    #pragma unroll
    for (int k = 0; k < KCH; ++k) mv[k] = ms[k * 64 + lane];

    // ---- Per-float4 masked inclusive prefix; chunk sums cs[k].
    float4 p[KCH];
    float  cs[KCH];
    #pragma unroll
    for (int k = 0; k < KCH; ++k) {
        float a0 = mv[k].x ? xv[k].x : 0.0f;
        float a1 = mv[k].y ? xv[k].y : 0.0f;
        float a2 = mv[k].z ? xv[k].z : 0.0f;
        float a3 = mv[k].w ? xv[k].w : 0.0f;
        p[k].x = a0;
        p[k].y = p[k].x + a1;
        p[k].z = p[k].y + a2;
        p[k].w = p[k].z + a3;
        cs[k]  = p[k].w;
    }

    // ---- 8 wave-scans (chunk order is k*64+lane), running carry.
    // excl[k] = exclusive prefix (within segment) of this lane's chunk k.
    float excl[KCH];
    float carry = 0.0f;
    #pragma unroll
    for (int k = 0; k < KCH; ++k) {
        float t = cs[k];
        #pragma unroll
        for (int d = 1; d < 64; d <<= 1) {
            float o = __shfl_up(t, d);
            if (lane >= d) t += o;
        }
        excl[k] = carry + (t - cs[k]);
        carry  += __shfl(t, 63);              // segment total so far
    }
    // carry == full segment masked sum (all lanes agree).

    // ---- Wave-level lookback: lane 0 polls predecessor, publishes own.
    float pre = 0.0f;
    if (lane == 0) {
        if (seg > 0) {
            const unsigned long long* slot =
                flags + (size_t)(seg - 1) * ROWS + row;
            unsigned long long v =
                __hip_atomic_load(slot, __ATOMIC_RELAXED, __HIP_MEMORY_SCOPE_AGENT);
            while (!(v >> 32)) {
                __builtin_amdgcn_s_sleep(1);
                v = __hip_atomic_load(slot, __ATOMIC_RELAXED, __HIP_MEMORY_SCOPE_AGENT);
            }
            pre = __uint_as_float((unsigned)v);
        }
        if (seg < NSEG - 1) {
            unsigned long long pk =
                (1ULL << 32) | (unsigned long long)__float_as_uint(pre + carry);
            __hip_atomic_store(flags + (size_t)seg * ROWS + row, pk,
                               __ATOMIC_RELAXED, __HIP_MEMORY_SCOPE_AGENT);
        }
    }
    pre = __shfl(pre, 0);                     // broadcast row prefix to wave

    // ---- Store.
    #pragma unroll
    for (int k = 0; k < KCH; ++k) {
        float off = pre + excl[k];
        os[k * 64 + lane] = make_float4(off + p[k].x, off + p[k].y,
                                        off + p[k].z, off + p[k].w);
    }
}

extern "C" void kernel_launch(void* const* d_in, const int* in_sizes, int n_in,
                              void* d_out, int out_size, void* d_ws, size_t ws_size,
                              hipStream_t stream) {
    const float* x    = (const float*)d_in[0];
    const int*   mask = (const int*)d_in[1];
    float*       out  = (float*)d_out;
    unsigned long long* flags = (unsigned long long*)d_ws;

    // Zero the ready flags every launch (capture-legal async op).
    (void)hipMemsetAsync(d_ws, 0,
                         (size_t)NSEG * ROWS * sizeof(unsigned long long), stream);

    masked_cumsum_wavechain<<<BPR * ROWS, THREADS, 0, stream>>>(x, mask, out, flags);
}